// Round 2
// baseline (5675.572 us; speedup 1.0000x reference)
//
#include <hip/hip_runtime.h>

#define N_NODES 50000
#define N_EDGES 800000
#define N_GRAPHS 1024
#define IN_DIM 78
#define HID 256
#define OUT_DIM 128

// ---------------- scatter-add aggregation (segment_sum over edges) -------------
__global__ __launch_bounds__(256)
void scatter_add_kernel(const float* __restrict__ feat,
                        const int* __restrict__ srcI,
                        const int* __restrict__ dstI,
                        float* __restrict__ out,
                        int nEdges, int D, int shiftP)
{
    long long total = (long long)nEdges << shiftP;
    int mask = (1 << shiftP) - 1;
    long long stride = (long long)gridDim.x * blockDim.x;
    for (long long i = (long long)blockIdx.x * blockDim.x + threadIdx.x; i < total; i += stride) {
        int f = (int)(i & mask);
        if (f < D) {
            int e = (int)(i >> shiftP);
            int s = srcI[e];
            int d = dstI[e];
            if ((unsigned)s < (unsigned)N_NODES && (unsigned)d < (unsigned)N_NODES) {
                atomicAdd(out + (long long)d * D + f, feat[(long long)s * D + f]);
            }
        }
    }
}

// ---------------- fused GraphConv GEMM: out = relu?(A1@W1 + A2@W2 + bias) ------
// 64x64 tile, BK=16, 256 threads, 4x4 micro-tile. out must NOT alias inputs.
__global__ __launch_bounds__(256)
void gemm_fused_kernel(const float* __restrict__ A1,
                       const float* __restrict__ A2,
                       const float* __restrict__ W1,
                       const float* __restrict__ W2,
                       const float* __restrict__ bias,
                       float* __restrict__ out,
                       int N, int K, int Fo, int do_relu)
{
    __shared__ float As[16][65];
    __shared__ float Bs[16][65];
    const int bm = blockIdx.y * 64;
    const int bn = blockIdx.x * 64;
    const int tid = (int)threadIdx.x;
    const int tx = tid & 15;
    const int ty = tid >> 4;
    float acc[4][4] = {};

    for (int pass = 0; pass < 2; ++pass) {
        const float* A = pass ? A2 : A1;
        const float* W = pass ? W2 : W1;
        if (A == nullptr) continue;
        for (int k0 = 0; k0 < K; k0 += 16) {
            {
                int m  = tid >> 2;
                int kb = (tid & 3) * 4;
                int row = bm + m;
                #pragma unroll
                for (int i = 0; i < 4; ++i) {
                    int k = k0 + kb + i;
                    As[kb + i][m] = (row < N && k < K) ? A[(long long)row * K + k] : 0.0f;
                }
            }
            {
                int k  = tid >> 4;
                int nb = (tid & 15) * 4;
                int kk = k0 + k;
                const float* Wrow = W + (long long)kk * Fo + bn + nb;
                #pragma unroll
                for (int i = 0; i < 4; ++i) {
                    Bs[k][nb + i] = (kk < K) ? Wrow[i] : 0.0f;
                }
            }
            __syncthreads();
            #pragma unroll
            for (int kk = 0; kk < 16; ++kk) {
                float a[4], b[4];
                #pragma unroll
                for (int i = 0; i < 4; ++i) a[i] = As[kk][ty * 4 + i];
                #pragma unroll
                for (int j = 0; j < 4; ++j) b[j] = Bs[kk][tx * 4 + j];
                #pragma unroll
                for (int i = 0; i < 4; ++i)
                    #pragma unroll
                    for (int j = 0; j < 4; ++j)
                        acc[i][j] += a[i] * b[j];
            }
            __syncthreads();
        }
    }

    #pragma unroll
    for (int i = 0; i < 4; ++i) {
        int row = bm + ty * 4 + i;
        if (row >= N) continue;
        #pragma unroll
        for (int j = 0; j < 4; ++j) {
            int col = bn + tx * 4 + j;
            float v = acc[i][j] + bias[col];
            if (do_relu) v = fmaxf(v, 0.0f);
            out[(long long)row * Fo + col] = v;
        }
    }
}

// ------------- in-place row-panel GEMM for layer 3 (K=512, Fo=512) -------------
// out may alias A1: each block owns 16 full rows; A1 panel is staged to LDS
// before any write; writes happen only after both passes complete.
// out = relu(A1@W1 + A2@W2 + bias). Requires N % 16 == 0.
__global__ __launch_bounds__(256)
void rowpanel_gemm512_kernel(const float* __restrict__ A1,
                             const float* __restrict__ A2,
                             const float* __restrict__ W1,
                             const float* __restrict__ W2,
                             const float* __restrict__ bias,
                             float* __restrict__ out)
{
    __shared__ float panel[16 * 512];   // 32 KB
    __shared__ float wtile[16 * 512];   // 32 KB
    const int r0 = blockIdx.x * 16;
    const int tid = (int)threadIdx.x;
    const int ty = tid >> 4;    // row 0..15
    const int tx = tid & 15;    // col group 0..15

    float acc[8][4];
    #pragma unroll
    for (int j = 0; j < 8; ++j)
        #pragma unroll
        for (int i = 0; i < 4; ++i) acc[j][i] = 0.0f;

    for (int pass = 0; pass < 2; ++pass) {
        const float* A = pass ? A2 : A1;
        const float* W = pass ? W2 : W1;
        __syncthreads();   // prior panel/wtile reads done
        {
            const float4* srcp = (const float4*)(A + (long long)r0 * 512);
            float4* dstp = (float4*)panel;
            #pragma unroll
            for (int i = 0; i < 8; ++i) dstp[tid + 256 * i] = srcp[tid + 256 * i];
        }
        for (int k0 = 0; k0 < 512; k0 += 16) {
            __syncthreads();   // prior wtile reads done (also covers panel store)
            {
                const float4* srcw = (const float4*)(W + (long long)k0 * 512);
                float4* dstw = (float4*)wtile;
                #pragma unroll
                for (int i = 0; i < 8; ++i) dstw[tid + 256 * i] = srcw[tid + 256 * i];
            }
            __syncthreads();
            const float* prow = panel + ty * 512 + k0;
            #pragma unroll
            for (int kk = 0; kk < 16; ++kk) {
                float a = prow[kk];
                const float4* wrow = (const float4*)(wtile + kk * 512);
                #pragma unroll
                for (int j = 0; j < 8; ++j) {
                    float4 w = wrow[tx + 16 * j];
                    acc[j][0] += a * w.x;
                    acc[j][1] += a * w.y;
                    acc[j][2] += a * w.z;
                    acc[j][3] += a * w.w;
                }
            }
        }
    }

    // epilogue: bias + relu + write own rows (safe to overwrite A1's rows now)
    float4* orow = (float4*)(out + (long long)(r0 + ty) * 512);
    const float4* b4 = (const float4*)bias;
    #pragma unroll
    for (int j = 0; j < 8; ++j) {
        float4 b = b4[tx + 16 * j];
        float4 v;
        v.x = fmaxf(acc[j][0] + b.x, 0.0f);
        v.y = fmaxf(acc[j][1] + b.y, 0.0f);
        v.z = fmaxf(acc[j][2] + b.z, 0.0f);
        v.w = fmaxf(acc[j][3] + b.w, 0.0f);
        orow[tx + 16 * j] = v;
    }
}

// ---------------- LayerNorm(128) + ReLU + write x_atom + atomic pool -----------
__global__ __launch_bounds__(128)
void ln_relu_pool_kernel(const float* __restrict__ z,
                         const float* __restrict__ gamma,
                         const float* __restrict__ beta,
                         const int* __restrict__ batch,
                         float* __restrict__ x_atom,
                         float* __restrict__ pooled)
{
    int row = (int)blockIdx.x;
    int t = (int)threadIdx.x;     // 0..127
    float v = z[(long long)row * 128 + t];

    __shared__ float red[2];
    float s = v;
    #pragma unroll
    for (int o = 32; o >= 1; o >>= 1) s += __shfl_xor(s, o, 64);
    int wave = t >> 6;
    if ((t & 63) == 0) red[wave] = s;
    __syncthreads();
    float mean = (red[0] + red[1]) * (1.0f / 128.0f);

    float d = v - mean;
    float s2 = d * d;
    #pragma unroll
    for (int o = 32; o >= 1; o >>= 1) s2 += __shfl_xor(s2, o, 64);
    __syncthreads();
    if ((t & 63) == 0) red[wave] = s2;
    __syncthreads();
    float var = (red[0] + red[1]) * (1.0f / 128.0f);

    float y = d * rsqrtf(var + 1e-5f) * gamma[t] + beta[t];
    y = fmaxf(y, 0.0f);
    x_atom[(long long)row * 128 + t] = y;
    int b = batch[row];
    if ((unsigned)b < (unsigned)N_GRAPHS)
        atomicAdd(pooled + (long long)b * 128 + t, y);
}

extern "C" void kernel_launch(void* const* d_in, const int* in_sizes, int n_in,
                              void* d_out, int out_size, void* d_ws, size_t ws_size,
                              hipStream_t stream)
{
    const float* x     = (const float*)d_in[0];
    const int*   ei    = (const int*)d_in[1];
    const int*   batch = (const int*)d_in[2];
    const float* W1r   = (const float*)d_in[3];
    const float* b1    = (const float*)d_in[4];
    const float* W1o   = (const float*)d_in[5];
    const float* W2r   = (const float*)d_in[6];
    const float* b2    = (const float*)d_in[7];
    const float* W2o   = (const float*)d_in[8];
    const float* W3r   = (const float*)d_in[9];
    const float* b3    = (const float*)d_in[10];
    const float* W3o   = (const float*)d_in[11];
    const float* Wfc   = (const float*)d_in[12];
    const float* bfc   = (const float*)d_in[13];
    const float* lng   = (const float*)d_in[14];
    const float* lnb   = (const float*)d_in[15];

    float* x_atom = (float*)d_out;
    float* pooled = x_atom + (size_t)N_NODES * OUT_DIM;

    // Workspace plan (204,800,000 bytes):
    //   A = ws + 0          (50000 x 256 f32 = 51.2e6 B)
    //   B = ws + 51.2e6 B   (50000 x 256 f32)
    //   C = ws + 102.4e6 B  (50000 x 512 f32 = 102.4e6 B)
    // A|B contiguous doubles as the 50000 x 512 aggr3 buffer (in-place h3).
    const size_t WS_NEED = 204800000;
    if (ws_size < WS_NEED) {
        // Diagnostic path: workspace too small for this plan — fail cleanly.
        hipMemsetAsync(d_out, 0, (size_t)out_size * sizeof(float), stream);
        return;
    }

    float* bufA = (float*)d_ws;
    float* bufB = bufA + (size_t)N_NODES * HID;        // +12.8e6 floats
    float* bufC = bufA + (size_t)N_NODES * 2 * HID;    // +25.6e6 floats
    float* aggr3 = bufA;                               // A|B spans 50000x512

    const int* src = ei;
    const int* dst = ei + N_EDGES;

    const int SC_BLOCKS = 262144;

    // ---------- layer 1: 78 -> 256 ----------
    hipMemsetAsync(bufA, 0, (size_t)N_NODES * IN_DIM * sizeof(float), stream);
    scatter_add_kernel<<<SC_BLOCKS, 256, 0, stream>>>(x, src, dst, bufA, N_EDGES, IN_DIM, 7);
    {
        dim3 g(HID / 64, (N_NODES + 63) / 64);
        gemm_fused_kernel<<<g, 256, 0, stream>>>(bufA, x, W1r, W1o, b1, bufB,
                                                 N_NODES, IN_DIM, HID, 1);
    }

    // ---------- layer 2: 256 -> 512 ----------
    hipMemsetAsync(bufA, 0, (size_t)N_NODES * HID * sizeof(float), stream);
    scatter_add_kernel<<<SC_BLOCKS, 256, 0, stream>>>(bufB, src, dst, bufA, N_EDGES, HID, 8);
    {
        dim3 g((2 * HID) / 64, (N_NODES + 63) / 64);
        gemm_fused_kernel<<<g, 256, 0, stream>>>(bufA, bufB, W2r, W2o, b2, bufC,
                                                 N_NODES, HID, 2 * HID, 1);
    }

    // ---------- layer 3: 512 -> 512 (aggr3 in A|B, h3 in-place over aggr3) -----
    hipMemsetAsync(aggr3, 0, (size_t)N_NODES * 2 * HID * sizeof(float), stream);
    scatter_add_kernel<<<SC_BLOCKS, 256, 0, stream>>>(bufC, src, dst, aggr3, N_EDGES, 2 * HID, 9);
    rowpanel_gemm512_kernel<<<N_NODES / 16, 256, 0, stream>>>(aggr3, bufC, W3r, W3o, b3, aggr3);

    // ---------- fc: 512 -> 128 (h3 = A|B, z -> C) ----------
    {
        dim3 g(OUT_DIM / 64, (N_NODES + 63) / 64);
        gemm_fused_kernel<<<g, 256, 0, stream>>>(aggr3, nullptr, Wfc, nullptr, bfc, bufC,
                                                 N_NODES, 2 * HID, OUT_DIM, 0);
    }

    // ---------- LayerNorm + ReLU + pool ----------
    hipMemsetAsync(pooled, 0, (size_t)N_GRAPHS * OUT_DIM * sizeof(float), stream);
    ln_relu_pool_kernel<<<N_NODES, 128, 0, stream>>>(bufC, lng, lnb, batch, x_atom, pooled);
}

// Round 3
// 1198.611 us; speedup vs baseline: 4.7351x; 4.7351x over previous
//
#include <hip/hip_runtime.h>

#define N_NODES 50000
#define N_EDGES 800000
#define N_GRAPHS 1024
#define IN_DIM 78
#define K1P 96            // IN_DIM padded to multiple of 32
#define HID 256
#define OUT_DIM 128

typedef unsigned short ushort_t;
typedef __attribute__((ext_vector_type(8))) short v8s;
typedef __attribute__((ext_vector_type(4))) float v4f;

__device__ __forceinline__ ushort_t f2bf(float f) {
    unsigned u = __float_as_uint(f);
    unsigned r = (u + 0x7fffu + ((u >> 16) & 1u)) >> 16;   // RNE
    return (ushort_t)r;
}
__device__ __forceinline__ float bf2f(ushort_t h) {
    return __uint_as_float((unsigned)h << 16);
}

#define GLOAD_LDS16(g, l) \
    __builtin_amdgcn_global_load_lds( \
        (const __attribute__((address_space(1))) unsigned int*)(g), \
        (__attribute__((address_space(3))) unsigned int*)(l), 16, 0, 0)

// ---------------- weight transpose + pad + bf16 cast: out[n][k] = W[k][n] ------
__global__ __launch_bounds__(256)
void wt_kernel(const float* __restrict__ W, ushort_t* __restrict__ out,
               int K, int N, int Kp)
{
    int i = blockIdx.x * 256 + threadIdx.x;
    if (i >= N * Kp) return;
    int n = i / Kp, k = i - n * Kp;
    float v = (k < K) ? W[(size_t)k * N + n] : 0.0f;
    out[i] = f2bf(v);
}

// ---------------- pad + cast activations: out[r][k<Kin?]=in, else 0 -----------
__global__ __launch_bounds__(256)
void pad_cast_kernel(const float* __restrict__ in, ushort_t* __restrict__ out,
                     int rows, int Kin, int Kout)
{
    int i = blockIdx.x * 256 + threadIdx.x;
    if (i >= rows * Kout) return;
    int r = i / Kout, k = i - r * Kout;
    out[i] = f2bf(k < Kin ? in[(size_t)r * Kin + k] : 0.0f);
}

// ---------------- CSR build ----------------------------------------------------
__global__ __launch_bounds__(256)
void hist_kernel(const int* __restrict__ dstI, int* __restrict__ deg, int nE)
{
    int e = blockIdx.x * 256 + threadIdx.x;
    if (e < nE) {
        int d = dstI[e];
        if ((unsigned)d < (unsigned)N_NODES) atomicAdd(&deg[d], 1);
    }
}

__global__ __launch_bounds__(1024)
void scan_kernel(const int* __restrict__ deg, int* __restrict__ rowptr, int n)
{
    __shared__ int s[1024];
    __shared__ int carry_s;
    int t = (int)threadIdx.x;
    if (t == 0) { carry_s = 0; rowptr[0] = 0; }
    __syncthreads();
    for (int base = 0; base < n; base += 1024) {
        int i = base + t;
        int v = (i < n) ? deg[i] : 0;
        s[t] = v;
        __syncthreads();
        for (int off = 1; off < 1024; off <<= 1) {
            int add = (t >= off) ? s[t - off] : 0;
            __syncthreads();
            s[t] += add;
            __syncthreads();
        }
        if (i < n) rowptr[i + 1] = s[t] + carry_s;
        __syncthreads();
        if (t == 1023) carry_s += s[1023];
        __syncthreads();
    }
}

__global__ __launch_bounds__(256)
void copy_int_kernel(const int* __restrict__ a, int* __restrict__ b, int n)
{
    int i = blockIdx.x * 256 + threadIdx.x;
    if (i < n) b[i] = a[i];
}

__global__ __launch_bounds__(256)
void fill_kernel(const int* __restrict__ srcI, const int* __restrict__ dstI,
                 int* __restrict__ cursor, int* __restrict__ csr_src, int nE)
{
    int e = blockIdx.x * 256 + threadIdx.x;
    if (e < nE) {
        int d = dstI[e];
        int s = srcI[e];
        if ((unsigned)d < (unsigned)N_NODES && (unsigned)s < (unsigned)N_NODES) {
            int pos = atomicAdd(&cursor[d], 1);
            csr_src[pos] = s;
        }
    }
}

// ---------------- CSR aggregation: out[n][:] = sum_{s in nbrs(n)} feat[s][:] ---
// bf16 in / fp32 accumulate / bf16 out. One block (256 thr) per node.
__global__ __launch_bounds__(256)
void csr_agg_kernel(const ushort_t* __restrict__ feat,
                    const int* __restrict__ rowptr,
                    const int* __restrict__ csr_src,
                    ushort_t* __restrict__ out, int Ds)
{
    int node = (int)blockIdx.x;
    int t = (int)threadIdx.x;
    int e0 = rowptr[node], e1 = rowptr[node + 1];
    int f0 = t, f1 = t + 256;
    float acc0 = 0.0f, acc1 = 0.0f;
    for (int e = e0; e < e1; ++e) {
        int s = csr_src[e];
        const ushort_t* row = feat + (size_t)s * Ds;
        if (f0 < Ds) acc0 += bf2f(row[f0]);
        if (f1 < Ds) acc1 += bf2f(row[f1]);
    }
    if (f0 < Ds) out[(size_t)node * Ds + f0] = f2bf(acc0);
    if (f1 < Ds) out[(size_t)node * Ds + f1] = f2bf(acc1);
}

// ---------------- bf16 MFMA GEMM (m97 recipe) ----------------------------------
// out = act( A1@W1t^T + A2@W2t^T + bias ),  A*: bf16 [M][K], W*t: bf16 [Fo][K]
// 128x128 tile, BK=32, 256 thr = 4 waves in 2x2, each wave 64x64 via 4x4 MFMA.
__global__ __launch_bounds__(256)
void mfma_gemm_kernel(const ushort_t* __restrict__ A1,
                      const ushort_t* __restrict__ A2,
                      const ushort_t* __restrict__ W1t,
                      const ushort_t* __restrict__ W2t,
                      const float* __restrict__ bias,
                      void* __restrict__ outp,
                      int M, int K, int Fo, int relu, int out_bf16)
{
    __shared__ ushort_t Al[8 * 512];   // 8 m-tiles x (16 rows x 32 k) lane-order
    __shared__ ushort_t Bl[8 * 512];
    const int tid = (int)threadIdx.x;
    const int l   = tid & 63;
    const int w   = tid >> 6;
    const int q   = l >> 4;
    const int r15 = l & 15;
    const int bm  = blockIdx.y * 128;
    const int bn  = blockIdx.x * 128;
    const int wm  = w >> 1, wn = w & 1;

    v4f acc[4][4];
    #pragma unroll
    for (int mt = 0; mt < 4; ++mt)
        #pragma unroll
        for (int nt = 0; nt < 4; ++nt)
            acc[mt][nt] = (v4f){0.0f, 0.0f, 0.0f, 0.0f};

    for (int pass = 0; pass < 2; ++pass) {
        const ushort_t* A  = pass ? A2  : A1;
        const ushort_t* Bt = pass ? W2t : W1t;
        if (A == nullptr) break;
        for (int k0 = 0; k0 < K; k0 += 32) {
            __syncthreads();   // prior frag reads done before LDS overwrite
            #pragma unroll
            for (int ii = 0; ii < 2; ++ii) {
                int it = w * 2 + ii;               // wave-uniform tile id
                int row = bm + it * 16 + r15;
                const ushort_t* ga = A + (size_t)row * K + k0 + q * 8;
                if (row < M) GLOAD_LDS16(ga, Al + it * 512);
                int col = bn + it * 16 + r15;      // Fo always multiple of 128
                const ushort_t* gb = Bt + (size_t)col * K + k0 + q * 8;
                GLOAD_LDS16(gb, Bl + it * 512);
            }
            __syncthreads();   // drains vmcnt -> staged data visible
            v8s af[4], bf[4];
            #pragma unroll
            for (int mt = 0; mt < 4; ++mt)
                af[mt] = *(const v8s*)(Al + (wm * 4 + mt) * 512 + l * 8);
            #pragma unroll
            for (int nt = 0; nt < 4; ++nt)
                bf[nt] = *(const v8s*)(Bl + (wn * 4 + nt) * 512 + l * 8);
            #pragma unroll
            for (int mt = 0; mt < 4; ++mt)
                #pragma unroll
                for (int nt = 0; nt < 4; ++nt)
                    acc[mt][nt] = __builtin_amdgcn_mfma_f32_16x16x32_bf16(
                        af[mt], bf[nt], acc[mt][nt], 0, 0, 0);
        }
    }

    // epilogue: C/D map col=lane&15, row=q*4+reg
    #pragma unroll
    for (int nt = 0; nt < 4; ++nt) {
        int col = bn + wn * 64 + nt * 16 + r15;
        float bb = bias[col];
        #pragma unroll
        for (int mt = 0; mt < 4; ++mt) {
            #pragma unroll
            for (int p = 0; p < 4; ++p) {
                int row = bm + wm * 64 + mt * 16 + q * 4 + p;
                if (row < M) {
                    float v = acc[mt][nt][p] + bb;
                    if (relu) v = fmaxf(v, 0.0f);
                    if (out_bf16) ((ushort_t*)outp)[(size_t)row * Fo + col] = f2bf(v);
                    else          ((float*)outp)[(size_t)row * Fo + col]   = v;
                }
            }
        }
    }
}

// ---------------- LayerNorm(128) + ReLU + x_atom + atomic pool -----------------
__global__ __launch_bounds__(128)
void ln_relu_pool_kernel(const float* __restrict__ z,
                         const float* __restrict__ gamma,
                         const float* __restrict__ beta,
                         const int* __restrict__ batch,
                         float* __restrict__ x_atom,
                         float* __restrict__ pooled)
{
    int row = (int)blockIdx.x;
    int t = (int)threadIdx.x;     // 0..127
    float v = z[(long long)row * 128 + t];

    __shared__ float red[2];
    float s = v;
    #pragma unroll
    for (int o = 32; o >= 1; o >>= 1) s += __shfl_xor(s, o, 64);
    int wave = t >> 6;
    if ((t & 63) == 0) red[wave] = s;
    __syncthreads();
    float mean = (red[0] + red[1]) * (1.0f / 128.0f);

    float d = v - mean;
    float s2 = d * d;
    #pragma unroll
    for (int o = 32; o >= 1; o >>= 1) s2 += __shfl_xor(s2, o, 64);
    __syncthreads();
    if ((t & 63) == 0) red[wave] = s2;
    __syncthreads();
    float var = (red[0] + red[1]) * (1.0f / 128.0f);

    float y = d * rsqrtf(var + 1e-5f) * gamma[t] + beta[t];
    y = fmaxf(y, 0.0f);
    x_atom[(long long)row * 128 + t] = y;
    int b = batch[row];
    if ((unsigned)b < (unsigned)N_GRAPHS)
        atomicAdd(pooled + (long long)b * 128 + t, y);
}

extern "C" void kernel_launch(void* const* d_in, const int* in_sizes, int n_in,
                              void* d_out, int out_size, void* d_ws, size_t ws_size,
                              hipStream_t stream)
{
    const float* x     = (const float*)d_in[0];
    const int*   ei    = (const int*)d_in[1];
    const int*   batch = (const int*)d_in[2];
    const float* W1r   = (const float*)d_in[3];
    const float* b1    = (const float*)d_in[4];
    const float* W1o   = (const float*)d_in[5];
    const float* W2r   = (const float*)d_in[6];
    const float* b2    = (const float*)d_in[7];
    const float* W2o   = (const float*)d_in[8];
    const float* W3r   = (const float*)d_in[9];
    const float* b3    = (const float*)d_in[10];
    const float* W3o   = (const float*)d_in[11];
    const float* Wfc   = (const float*)d_in[12];
    const float* bfc   = (const float*)d_in[13];
    const float* lng   = (const float*)d_in[14];
    const float* lnb   = (const float*)d_in[15];

    const size_t WS_NEED = 204800000;
    if (ws_size < WS_NEED) {
        hipMemsetAsync(d_out, 0, (size_t)out_size * sizeof(float), stream);
        return;
    }

    char* ws = (char*)d_ws;
    // layout (bytes)
    ushort_t* xb   = (ushort_t*)(ws + 0);            // 50000x96 bf16   = 9.6e6
    ushort_t* h1   = (ushort_t*)(ws + 9600000);      // 50000x256 bf16  = 25.6e6
    float*    z    = (float*)   (ws + 0);            // 50000x128 f32 (xb/h1 dead)
    ushort_t* aggr = (ushort_t*)(ws + 35200000);     // up to 50000x512 bf16
    ushort_t* h2   = (ushort_t*)(ws + 86400000);     // 50000x512 bf16
    ushort_t* h3   = (ushort_t*)(ws + 137600000);    // 50000x512 bf16
    int* deg    = (int*)(ws + 188800000);            // 50000
    int* rowptr = (int*)(ws + 189000000);            // 50001
    int* cursor = (int*)(ws + 189200128);            // 50000
    int* csrsrc = (int*)(ws + 189400128);            // 800000
    ushort_t* wt = (ushort_t*)(ws + 192600128);
    ushort_t* w1r_t = wt;                 // 256x96
    ushort_t* w1o_t = w1r_t + 24576;      // 256x96
    ushort_t* w2r_t = w1o_t + 24576;      // 512x256
    ushort_t* w2o_t = w2r_t + 131072;     // 512x256
    ushort_t* w3r_t = w2o_t + 131072;     // 512x512
    ushort_t* w3o_t = w3r_t + 262144;     // 512x512
    ushort_t* wfc_t = w3o_t + 262144;     // 128x512

    float* x_atom = (float*)d_out;
    float* pooled = x_atom + (size_t)N_NODES * OUT_DIM;

    const int* src = ei;
    const int* dst = ei + N_EDGES;

    // ---- conversions: weights (transpose+pad+bf16), x (pad+bf16) ----
    wt_kernel<<<(256 * K1P + 255) / 256, 256, 0, stream>>>(W1r, w1r_t, IN_DIM, HID, K1P);
    wt_kernel<<<(256 * K1P + 255) / 256, 256, 0, stream>>>(W1o, w1o_t, IN_DIM, HID, K1P);
    wt_kernel<<<(512 * 256 + 255) / 256, 256, 0, stream>>>(W2r, w2r_t, HID, 2 * HID, HID);
    wt_kernel<<<(512 * 256 + 255) / 256, 256, 0, stream>>>(W2o, w2o_t, HID, 2 * HID, HID);
    wt_kernel<<<(512 * 512 + 255) / 256, 256, 0, stream>>>(W3r, w3r_t, 2 * HID, 2 * HID, 2 * HID);
    wt_kernel<<<(512 * 512 + 255) / 256, 256, 0, stream>>>(W3o, w3o_t, 2 * HID, 2 * HID, 2 * HID);
    wt_kernel<<<(128 * 512 + 255) / 256, 256, 0, stream>>>(Wfc, wfc_t, 2 * HID, OUT_DIM, 2 * HID);
    pad_cast_kernel<<<((N_NODES * K1P) + 255) / 256, 256, 0, stream>>>(x, xb, N_NODES, IN_DIM, K1P);

    // ---- CSR build ----
    hipMemsetAsync(deg, 0, N_NODES * sizeof(int), stream);
    hist_kernel<<<(N_EDGES + 255) / 256, 256, 0, stream>>>(dst, deg, N_EDGES);
    scan_kernel<<<1, 1024, 0, stream>>>(deg, rowptr, N_NODES);
    copy_int_kernel<<<(N_NODES + 255) / 256, 256, 0, stream>>>(rowptr, cursor, N_NODES);
    fill_kernel<<<(N_EDGES + 255) / 256, 256, 0, stream>>>(src, dst, cursor, csrsrc, N_EDGES);

    const int GY = (N_NODES + 127) / 128;

    // ---- layer 1: 78(pad96) -> 256 ----
    csr_agg_kernel<<<N_NODES, 256, 0, stream>>>(xb, rowptr, csrsrc, aggr, K1P);
    {
        dim3 g(HID / 128, GY);
        mfma_gemm_kernel<<<g, 256, 0, stream>>>(aggr, xb, w1r_t, w1o_t, b1, h1,
                                                N_NODES, K1P, HID, 1, 1);
    }
    // ---- layer 2: 256 -> 512 ----
    csr_agg_kernel<<<N_NODES, 256, 0, stream>>>(h1, rowptr, csrsrc, aggr, HID);
    {
        dim3 g((2 * HID) / 128, GY);
        mfma_gemm_kernel<<<g, 256, 0, stream>>>(aggr, h1, w2r_t, w2o_t, b2, h2,
                                                N_NODES, HID, 2 * HID, 1, 1);
    }
    // ---- layer 3: 512 -> 512 ----
    csr_agg_kernel<<<N_NODES, 256, 0, stream>>>(h2, rowptr, csrsrc, aggr, 2 * HID);
    {
        dim3 g((2 * HID) / 128, GY);
        mfma_gemm_kernel<<<g, 256, 0, stream>>>(aggr, h2, w3r_t, w3o_t, b3, h3,
                                                N_NODES, 2 * HID, 2 * HID, 1, 1);
    }
    // ---- fc: 512 -> 128, fp32 out, no relu ----
    {
        dim3 g(OUT_DIM / 128, GY);
        mfma_gemm_kernel<<<g, 256, 0, stream>>>(h3, nullptr, wfc_t, nullptr, bfc, z,
                                                N_NODES, 2 * HID, OUT_DIM, 0, 0);
    }
    // ---- LN + ReLU + pool ----
    hipMemsetAsync(pooled, 0, (size_t)N_GRAPHS * OUT_DIM * sizeof(float), stream);
    ln_relu_pool_kernel<<<N_NODES, 128, 0, stream>>>(z, lng, lnb, batch, x_atom, pooled);
}

// Round 4
// 753.983 us; speedup vs baseline: 7.5275x; 1.5897x over previous
//
#include <hip/hip_runtime.h>

#define N_NODES 50000
#define N_EDGES 800000
#define N_GRAPHS 1024
#define IN_DIM 78
#define K1P 96            // IN_DIM padded to multiple of 32
#define HID 256
#define OUT_DIM 128

typedef unsigned short ushort_t;
typedef __attribute__((ext_vector_type(8))) short v8s;
typedef __attribute__((ext_vector_type(4))) float v4f;
typedef __attribute__((ext_vector_type(2))) unsigned short us2;
typedef __attribute__((ext_vector_type(4))) unsigned short us4;
typedef __attribute__((ext_vector_type(8))) unsigned short us8;

__device__ __forceinline__ ushort_t f2bf(float f) {
    unsigned u = __float_as_uint(f);
    unsigned r = (u + 0x7fffu + ((u >> 16) & 1u)) >> 16;   // RNE
    return (ushort_t)r;
}
__device__ __forceinline__ float bf2f(ushort_t h) {
    return __uint_as_float((unsigned)h << 16);
}

#define GLOAD_LDS16(g, l) \
    __builtin_amdgcn_global_load_lds( \
        (const __attribute__((address_space(1))) unsigned int*)(g), \
        (__attribute__((address_space(3))) unsigned int*)(l), 16, 0, 0)

// ---------------- weight transpose + pad + bf16 cast: out[n][k] = W[k][n] ------
__global__ __launch_bounds__(256)
void wt_kernel(const float* __restrict__ W, ushort_t* __restrict__ out,
               int K, int N, int Kp)
{
    int i = blockIdx.x * 256 + threadIdx.x;
    if (i >= N * Kp) return;
    int n = i / Kp, k = i - n * Kp;
    float v = (k < K) ? W[(size_t)k * N + n] : 0.0f;
    out[i] = f2bf(v);
}

// ---------------- pad + cast activations: out[r][k<Kin?]=in, else 0 -----------
__global__ __launch_bounds__(256)
void pad_cast_kernel(const float* __restrict__ in, ushort_t* __restrict__ out,
                     int rows, int Kin, int Kout)
{
    int i = blockIdx.x * 256 + threadIdx.x;
    if (i >= rows * Kout) return;
    int r = i / Kout, k = i - r * Kout;
    out[i] = f2bf(k < Kin ? in[(size_t)r * Kin + k] : 0.0f);
}

// ---------------- CSR build ----------------------------------------------------
__global__ __launch_bounds__(256)
void hist_kernel(const int* __restrict__ dstI, int* __restrict__ deg, int nE)
{
    int e = blockIdx.x * 256 + threadIdx.x;
    if (e < nE) {
        int d = dstI[e];
        if ((unsigned)d < (unsigned)N_NODES) atomicAdd(&deg[d], 1);
    }
}

// hierarchical exclusive scan of deg -> rowptr (n+1 entries)
__global__ __launch_bounds__(1024)
void scan1_kernel(const int* __restrict__ deg, int* __restrict__ rowptr,
                  int* __restrict__ blocksum, int n)
{
    __shared__ int s[1024];
    int b = (int)blockIdx.x, t = (int)threadIdx.x;
    int i = b * 1024 + t;
    int v = (i < n) ? deg[i] : 0;
    s[t] = v;
    __syncthreads();
    for (int off = 1; off < 1024; off <<= 1) {
        int a = (t >= off) ? s[t - off] : 0;
        __syncthreads();
        s[t] += a;
        __syncthreads();
    }
    if (i < n) rowptr[i + 1] = s[t];      // block-local inclusive
    if (t == 1023) blocksum[b] = s[1023];
    if (b == 0 && t == 0) rowptr[0] = 0;
}

__global__ __launch_bounds__(64)
void scan2_kernel(int* __restrict__ blocksum, int nb)   // nb <= 64
{
    int t = (int)threadIdx.x;
    int v = (t < nb) ? blocksum[t] : 0;
    #pragma unroll
    for (int off = 1; off < 64; off <<= 1) {
        int a = __shfl_up(v, off, 64);
        if (t >= off) v += a;
    }
    if (t < nb) blocksum[t] = v;
}

__global__ __launch_bounds__(256)
void scan3_kernel(const int* __restrict__ blocksum, int* __restrict__ rowptr,
                  int* __restrict__ cursor, int n)
{
    int j = blockIdx.x * 256 + threadIdx.x;   // 0..n
    if (j > n) return;
    int v;
    if (j == 0) v = 0;
    else {
        int b = (j - 1) >> 10;
        v = rowptr[j] + (b >= 1 ? blocksum[b - 1] : 0);
    }
    rowptr[j] = v;
    if (j < n) cursor[j] = v;
}

__global__ __launch_bounds__(256)
void fill_kernel(const int* __restrict__ srcI, const int* __restrict__ dstI,
                 int* __restrict__ cursor, int* __restrict__ csr_src, int nE)
{
    int e = blockIdx.x * 256 + threadIdx.x;
    if (e < nE) {
        int d = dstI[e];
        int s = srcI[e];
        if ((unsigned)d < (unsigned)N_NODES && (unsigned)s < (unsigned)N_NODES) {
            int pos = atomicAdd(&cursor[d], 1);
            csr_src[pos] = s;
        }
    }
}

// ---------------- CSR aggregation, wave-per-node, vectorized gathers -----------
// One 64-lane wave per node; lane owns VPT contiguous bf16 (VPT*2 bytes/lane).
// fp32 accumulate, 4-edge unroll for MLP. bf16 out.
template<int VPT> struct VecT;
template<> struct VecT<2> { using T = us2; };
template<> struct VecT<4> { using T = us4; };
template<> struct VecT<8> { using T = us8; };

template<int VPT>
__global__ __launch_bounds__(256)
void csr_agg_wave_kernel(const ushort_t* __restrict__ feat,
                         const int* __restrict__ rowptr,
                         const int* __restrict__ csr_src,
                         ushort_t* __restrict__ out, int Ds)
{
    using T = typename VecT<VPT>::T;
    const int wv   = (int)threadIdx.x >> 6;
    const int node = (int)blockIdx.x * 4 + wv;
    if (node >= N_NODES) return;
    const int lane = (int)threadIdx.x & 63;
    const int off0 = lane * VPT;
    const bool act = off0 < Ds;                    // Ds=96: lanes 48..63 idle
    const int off  = act ? off0 : (Ds - VPT);      // clamp: redundant but safe

    const int e0 = rowptr[node], e1 = rowptr[node + 1];
    float acc[VPT];
    #pragma unroll
    for (int i = 0; i < VPT; ++i) acc[i] = 0.0f;

    int e = e0;
    for (; e + 4 <= e1; e += 4) {
        int s0 = csr_src[e + 0];
        int s1 = csr_src[e + 1];
        int s2 = csr_src[e + 2];
        int s3 = csr_src[e + 3];
        T r0 = *(const T*)(feat + (size_t)s0 * Ds + off);
        T r1 = *(const T*)(feat + (size_t)s1 * Ds + off);
        T r2 = *(const T*)(feat + (size_t)s2 * Ds + off);
        T r3 = *(const T*)(feat + (size_t)s3 * Ds + off);
        #pragma unroll
        for (int i = 0; i < VPT; ++i)
            acc[i] += (bf2f(r0[i]) + bf2f(r1[i])) + (bf2f(r2[i]) + bf2f(r3[i]));
    }
    for (; e < e1; ++e) {
        int s = csr_src[e];
        T r = *(const T*)(feat + (size_t)s * Ds + off);
        #pragma unroll
        for (int i = 0; i < VPT; ++i) acc[i] += bf2f(r[i]);
    }

    if (act) {
        T o;
        #pragma unroll
        for (int i = 0; i < VPT; ++i) o[i] = f2bf(acc[i]);
        *(T*)(out + (size_t)node * Ds + off0) = o;
    }
}

// ---------------- bf16 MFMA GEMM (m97 recipe) ----------------------------------
// out = act( A1@W1t^T + A2@W2t^T + bias ),  A*: bf16 [M][K], W*t: bf16 [Fo][K]
// 128x128 tile, BK=32, 256 thr = 4 waves in 2x2, each wave 64x64 via 4x4 MFMA.
__global__ __launch_bounds__(256)
void mfma_gemm_kernel(const ushort_t* __restrict__ A1,
                      const ushort_t* __restrict__ A2,
                      const ushort_t* __restrict__ W1t,
                      const ushort_t* __restrict__ W2t,
                      const float* __restrict__ bias,
                      void* __restrict__ outp,
                      int M, int K, int Fo, int relu, int out_bf16)
{
    __shared__ ushort_t Al[8 * 512];   // 8 m-tiles x (16 rows x 32 k) lane-order
    __shared__ ushort_t Bl[8 * 512];
    const int tid = (int)threadIdx.x;
    const int l   = tid & 63;
    const int w   = tid >> 6;
    const int q   = l >> 4;
    const int r15 = l & 15;
    const int bm  = blockIdx.y * 128;
    const int bn  = blockIdx.x * 128;
    const int wm  = w >> 1, wn = w & 1;

    v4f acc[4][4];
    #pragma unroll
    for (int mt = 0; mt < 4; ++mt)
        #pragma unroll
        for (int nt = 0; nt < 4; ++nt)
            acc[mt][nt] = (v4f){0.0f, 0.0f, 0.0f, 0.0f};

    for (int pass = 0; pass < 2; ++pass) {
        const ushort_t* A  = pass ? A2  : A1;
        const ushort_t* Bt = pass ? W2t : W1t;
        if (A == nullptr) break;
        for (int k0 = 0; k0 < K; k0 += 32) {
            __syncthreads();   // prior frag reads done before LDS overwrite
            #pragma unroll
            for (int ii = 0; ii < 2; ++ii) {
                int it = w * 2 + ii;               // wave-uniform tile id
                int row = bm + it * 16 + r15;
                const ushort_t* ga = A + (size_t)row * K + k0 + q * 8;
                if (row < M) GLOAD_LDS16(ga, Al + it * 512);
                int col = bn + it * 16 + r15;      // Fo always multiple of 128
                const ushort_t* gb = Bt + (size_t)col * K + k0 + q * 8;
                GLOAD_LDS16(gb, Bl + it * 512);
            }
            __syncthreads();   // drains vmcnt -> staged data visible
            v8s af[4], bf[4];
            #pragma unroll
            for (int mt = 0; mt < 4; ++mt)
                af[mt] = *(const v8s*)(Al + (wm * 4 + mt) * 512 + l * 8);
            #pragma unroll
            for (int nt = 0; nt < 4; ++nt)
                bf[nt] = *(const v8s*)(Bl + (wn * 4 + nt) * 512 + l * 8);
            #pragma unroll
            for (int mt = 0; mt < 4; ++mt)
                #pragma unroll
                for (int nt = 0; nt < 4; ++nt)
                    acc[mt][nt] = __builtin_amdgcn_mfma_f32_16x16x32_bf16(
                        af[mt], bf[nt], acc[mt][nt], 0, 0, 0);
        }
    }

    // epilogue: C/D map col=lane&15, row=q*4+reg
    #pragma unroll
    for (int nt = 0; nt < 4; ++nt) {
        int col = bn + wn * 64 + nt * 16 + r15;
        float bb = bias[col];
        #pragma unroll
        for (int mt = 0; mt < 4; ++mt) {
            #pragma unroll
            for (int p = 0; p < 4; ++p) {
                int row = bm + wm * 64 + mt * 16 + q * 4 + p;
                if (row < M) {
                    float v = acc[mt][nt][p] + bb;
                    if (relu) v = fmaxf(v, 0.0f);
                    if (out_bf16) ((ushort_t*)outp)[(size_t)row * Fo + col] = f2bf(v);
                    else          ((float*)outp)[(size_t)row * Fo + col]   = v;
                }
            }
        }
    }
}

// ---------------- LayerNorm(128) + ReLU + x_atom + atomic pool -----------------
__global__ __launch_bounds__(128)
void ln_relu_pool_kernel(const float* __restrict__ z,
                         const float* __restrict__ gamma,
                         const float* __restrict__ beta,
                         const int* __restrict__ batch,
                         float* __restrict__ x_atom,
                         float* __restrict__ pooled)
{
    int row = (int)blockIdx.x;
    int t = (int)threadIdx.x;     // 0..127
    float v = z[(long long)row * 128 + t];

    __shared__ float red[2];
    float s = v;
    #pragma unroll
    for (int o = 32; o >= 1; o >>= 1) s += __shfl_xor(s, o, 64);
    int wave = t >> 6;
    if ((t & 63) == 0) red[wave] = s;
    __syncthreads();
    float mean = (red[0] + red[1]) * (1.0f / 128.0f);

    float d = v - mean;
    float s2 = d * d;
    #pragma unroll
    for (int o = 32; o >= 1; o >>= 1) s2 += __shfl_xor(s2, o, 64);
    __syncthreads();
    if ((t & 63) == 0) red[wave] = s2;
    __syncthreads();
    float var = (red[0] + red[1]) * (1.0f / 128.0f);

    float y = d * rsqrtf(var + 1e-5f) * gamma[t] + beta[t];
    y = fmaxf(y, 0.0f);
    x_atom[(long long)row * 128 + t] = y;
    int b = batch[row];
    if ((unsigned)b < (unsigned)N_GRAPHS)
        atomicAdd(pooled + (long long)b * 128 + t, y);
}

extern "C" void kernel_launch(void* const* d_in, const int* in_sizes, int n_in,
                              void* d_out, int out_size, void* d_ws, size_t ws_size,
                              hipStream_t stream)
{
    const float* x     = (const float*)d_in[0];
    const int*   ei    = (const int*)d_in[1];
    const int*   batch = (const int*)d_in[2];
    const float* W1r   = (const float*)d_in[3];
    const float* b1    = (const float*)d_in[4];
    const float* W1o   = (const float*)d_in[5];
    const float* W2r   = (const float*)d_in[6];
    const float* b2    = (const float*)d_in[7];
    const float* W2o   = (const float*)d_in[8];
    const float* W3r   = (const float*)d_in[9];
    const float* b3    = (const float*)d_in[10];
    const float* W3o   = (const float*)d_in[11];
    const float* Wfc   = (const float*)d_in[12];
    const float* bfc   = (const float*)d_in[13];
    const float* lng   = (const float*)d_in[14];
    const float* lnb   = (const float*)d_in[15];

    const size_t WS_NEED = 204800000;
    if (ws_size < WS_NEED) {
        hipMemsetAsync(d_out, 0, (size_t)out_size * sizeof(float), stream);
        return;
    }

    char* ws = (char*)d_ws;
    // layout (bytes)
    ushort_t* xb   = (ushort_t*)(ws + 0);            // 50000x96 bf16   = 9.6e6
    ushort_t* h1   = (ushort_t*)(ws + 9600000);      // 50000x256 bf16  = 25.6e6
    float*    z    = (float*)   (ws + 0);            // 50000x128 f32 (xb/h1 dead)
    ushort_t* aggr = (ushort_t*)(ws + 35200000);     // up to 50000x512 bf16
    ushort_t* h2   = (ushort_t*)(ws + 86400000);     // 50000x512 bf16
    ushort_t* h3   = (ushort_t*)(ws + 137600000);    // 50000x512 bf16
    int* deg    = (int*)(ws + 188800000);            // 50000
    int* rowptr = (int*)(ws + 189000000);            // 50001
    int* cursor = (int*)(ws + 189200128);            // 50000
    int* csrsrc = (int*)(ws + 189400128);            // 800000
    int* blksum = (int*)(ws + 192600128);            // 64
    ushort_t* wt = (ushort_t*)(ws + 192600512);
    ushort_t* w1r_t = wt;                 // 256x96
    ushort_t* w1o_t = w1r_t + 24576;      // 256x96
    ushort_t* w2r_t = w1o_t + 24576;      // 512x256
    ushort_t* w2o_t = w2r_t + 131072;     // 512x256
    ushort_t* w3r_t = w2o_t + 131072;     // 512x512
    ushort_t* w3o_t = w3r_t + 262144;     // 512x512
    ushort_t* wfc_t = w3o_t + 262144;     // 128x512

    float* x_atom = (float*)d_out;
    float* pooled = x_atom + (size_t)N_NODES * OUT_DIM;

    const int* src = ei;
    const int* dst = ei + N_EDGES;

    // ---- conversions: weights (transpose+pad+bf16), x (pad+bf16) ----
    wt_kernel<<<(256 * K1P + 255) / 256, 256, 0, stream>>>(W1r, w1r_t, IN_DIM, HID, K1P);
    wt_kernel<<<(256 * K1P + 255) / 256, 256, 0, stream>>>(W1o, w1o_t, IN_DIM, HID, K1P);
    wt_kernel<<<(512 * 256 + 255) / 256, 256, 0, stream>>>(W2r, w2r_t, HID, 2 * HID, HID);
    wt_kernel<<<(512 * 256 + 255) / 256, 256, 0, stream>>>(W2o, w2o_t, HID, 2 * HID, HID);
    wt_kernel<<<(512 * 512 + 255) / 256, 256, 0, stream>>>(W3r, w3r_t, 2 * HID, 2 * HID, 2 * HID);
    wt_kernel<<<(512 * 512 + 255) / 256, 256, 0, stream>>>(W3o, w3o_t, 2 * HID, 2 * HID, 2 * HID);
    wt_kernel<<<(128 * 512 + 255) / 256, 256, 0, stream>>>(Wfc, wfc_t, 2 * HID, OUT_DIM, 2 * HID);
    pad_cast_kernel<<<((N_NODES * K1P) + 255) / 256, 256, 0, stream>>>(x, xb, N_NODES, IN_DIM, K1P);

    // ---- CSR build ----
    hipMemsetAsync(deg, 0, N_NODES * sizeof(int), stream);
    hist_kernel<<<(N_EDGES + 255) / 256, 256, 0, stream>>>(dst, deg, N_EDGES);
    {
        int nb = (N_NODES + 1023) / 1024;   // 49
        scan1_kernel<<<nb, 1024, 0, stream>>>(deg, rowptr, blksum, N_NODES);
        scan2_kernel<<<1, 64, 0, stream>>>(blksum, nb);
        scan3_kernel<<<(N_NODES + 1 + 255) / 256, 256, 0, stream>>>(blksum, rowptr, cursor, N_NODES);
    }
    fill_kernel<<<(N_EDGES + 255) / 256, 256, 0, stream>>>(src, dst, cursor, csrsrc, N_EDGES);

    const int GY = (N_NODES + 127) / 128;
    const int AGG_BLKS = (N_NODES + 3) / 4;

    // ---- layer 1: 78(pad96) -> 256 ----
    csr_agg_wave_kernel<2><<<AGG_BLKS, 256, 0, stream>>>(xb, rowptr, csrsrc, aggr, K1P);
    {
        dim3 g(HID / 128, GY);
        mfma_gemm_kernel<<<g, 256, 0, stream>>>(aggr, xb, w1r_t, w1o_t, b1, h1,
                                                N_NODES, K1P, HID, 1, 1);
    }
    // ---- layer 2: 256 -> 512 ----
    csr_agg_wave_kernel<4><<<AGG_BLKS, 256, 0, stream>>>(h1, rowptr, csrsrc, aggr, HID);
    {
        dim3 g((2 * HID) / 128, GY);
        mfma_gemm_kernel<<<g, 256, 0, stream>>>(aggr, h1, w2r_t, w2o_t, b2, h2,
                                                N_NODES, HID, 2 * HID, 1, 1);
    }
    // ---- layer 3: 512 -> 512 ----
    csr_agg_wave_kernel<8><<<AGG_BLKS, 256, 0, stream>>>(h2, rowptr, csrsrc, aggr, 2 * HID);
    {
        dim3 g((2 * HID) / 128, GY);
        mfma_gemm_kernel<<<g, 256, 0, stream>>>(aggr, h2, w3r_t, w3o_t, b3, h3,
                                                N_NODES, 2 * HID, 2 * HID, 1, 1);
    }
    // ---- fc: 512 -> 128, fp32 out, no relu ----
    {
        dim3 g(OUT_DIM / 128, GY);
        mfma_gemm_kernel<<<g, 256, 0, stream>>>(h3, nullptr, wfc_t, nullptr, bfc, z,
                                                N_NODES, 2 * HID, OUT_DIM, 0, 0);
    }
    // ---- LN + ReLU + pool ----
    hipMemsetAsync(pooled, 0, (size_t)N_GRAPHS * OUT_DIM * sizeof(float), stream);
    ln_relu_pool_kernel<<<N_NODES, 128, 0, stream>>>(z, lng, lnb, batch, x_atom, pooled);
}

// Round 5
// 718.064 us; speedup vs baseline: 7.9040x; 1.0500x over previous
//
#include <hip/hip_runtime.h>

#define N_NODES 50000
#define N_EDGES 800000
#define N_GRAPHS 1024
#define IN_DIM 78
#define K1P 96            // IN_DIM padded to multiple of 32
#define HID 256
#define OUT_DIM 128

typedef unsigned short ushort_t;
typedef __attribute__((ext_vector_type(8))) short v8s;
typedef __attribute__((ext_vector_type(4))) float v4f;
typedef __attribute__((ext_vector_type(2))) unsigned short us2;
typedef __attribute__((ext_vector_type(4))) unsigned short us4;
typedef __attribute__((ext_vector_type(8))) unsigned short us8;

__device__ __forceinline__ ushort_t f2bf(float f) {
    unsigned u = __float_as_uint(f);
    unsigned r = (u + 0x7fffu + ((u >> 16) & 1u)) >> 16;   // RNE
    return (ushort_t)r;
}
__device__ __forceinline__ float bf2f(ushort_t h) {
    return __uint_as_float((unsigned)h << 16);
}

#define GLOAD_LDS16(g, l) \
    __builtin_amdgcn_global_load_lds( \
        (const __attribute__((address_space(1))) unsigned int*)(g), \
        (__attribute__((address_space(3))) unsigned int*)(l), 16, 0, 0)

// ---------------- weight transpose + pad + bf16 cast: out[n][k] = W[k][n] ------
__global__ __launch_bounds__(256)
void wt_kernel(const float* __restrict__ W, ushort_t* __restrict__ out,
               int K, int N, int Kp)
{
    int i = blockIdx.x * 256 + threadIdx.x;
    if (i >= N * Kp) return;
    int n = i / Kp, k = i - n * Kp;
    float v = (k < K) ? W[(size_t)k * N + n] : 0.0f;
    out[i] = f2bf(v);
}

// ---------------- pad + cast activations: out[r][k<Kin?]=in, else 0 -----------
__global__ __launch_bounds__(256)
void pad_cast_kernel(const float* __restrict__ in, ushort_t* __restrict__ out,
                     int rows, int Kin, int Kout)
{
    int i = blockIdx.x * 256 + threadIdx.x;
    if (i >= rows * Kout) return;
    int r = i / Kout, k = i - r * Kout;
    out[i] = f2bf(k < Kin ? in[(size_t)r * Kin + k] : 0.0f);
}

// ---------------- CSR build ----------------------------------------------------
__global__ __launch_bounds__(256)
void hist_kernel(const int* __restrict__ dstI, int* __restrict__ deg, int nE)
{
    int e = blockIdx.x * 256 + threadIdx.x;
    if (e < nE) {
        int d = dstI[e];
        if ((unsigned)d < (unsigned)N_NODES) atomicAdd(&deg[d], 1);
    }
}

// hierarchical exclusive scan of deg -> rowptr (n+1 entries)
__global__ __launch_bounds__(1024)
void scan1_kernel(const int* __restrict__ deg, int* __restrict__ rowptr,
                  int* __restrict__ blocksum, int n)
{
    __shared__ int s[1024];
    int b = (int)blockIdx.x, t = (int)threadIdx.x;
    int i = b * 1024 + t;
    int v = (i < n) ? deg[i] : 0;
    s[t] = v;
    __syncthreads();
    for (int off = 1; off < 1024; off <<= 1) {
        int a = (t >= off) ? s[t - off] : 0;
        __syncthreads();
        s[t] += a;
        __syncthreads();
    }
    if (i < n) rowptr[i + 1] = s[t];      // block-local inclusive
    if (t == 1023) blocksum[b] = s[1023];
    if (b == 0 && t == 0) rowptr[0] = 0;
}

__global__ __launch_bounds__(64)
void scan2_kernel(int* __restrict__ blocksum, int nb)   // nb <= 64
{
    int t = (int)threadIdx.x;
    int v = (t < nb) ? blocksum[t] : 0;
    #pragma unroll
    for (int off = 1; off < 64; off <<= 1) {
        int a = __shfl_up(v, off, 64);
        if (t >= off) v += a;
    }
    if (t < nb) blocksum[t] = v;
}

__global__ __launch_bounds__(256)
void scan3_kernel(const int* __restrict__ blocksum, int* __restrict__ rowptr,
                  int* __restrict__ cursor, int n)
{
    int j = blockIdx.x * 256 + threadIdx.x;   // 0..n
    if (j > n) return;
    int v;
    if (j == 0) v = 0;
    else {
        int b = (j - 1) >> 10;
        v = rowptr[j] + (b >= 1 ? blocksum[b - 1] : 0);
    }
    rowptr[j] = v;
    if (j < n) cursor[j] = v;
}

__global__ __launch_bounds__(256)
void fill_kernel(const int* __restrict__ srcI, const int* __restrict__ dstI,
                 int* __restrict__ cursor, int* __restrict__ csr_src, int nE)
{
    int e = blockIdx.x * 256 + threadIdx.x;
    if (e < nE) {
        int d = dstI[e];
        int s = srcI[e];
        if ((unsigned)d < (unsigned)N_NODES && (unsigned)s < (unsigned)N_NODES) {
            int pos = atomicAdd(&cursor[d], 1);
            csr_src[pos] = s;
        }
    }
}

// ---------------- CSR aggregation, wave-per-node, vectorized gathers -----------
template<int VPT> struct VecT;
template<> struct VecT<2> { using T = us2; };
template<> struct VecT<4> { using T = us4; };
template<> struct VecT<8> { using T = us8; };

template<int VPT>
__global__ __launch_bounds__(256)
void csr_agg_wave_kernel(const ushort_t* __restrict__ feat,
                         const int* __restrict__ rowptr,
                         const int* __restrict__ csr_src,
                         ushort_t* __restrict__ out, int Ds)
{
    using T = typename VecT<VPT>::T;
    const int wv   = (int)threadIdx.x >> 6;
    const int node = (int)blockIdx.x * 4 + wv;
    if (node >= N_NODES) return;
    const int lane = (int)threadIdx.x & 63;
    const int off0 = lane * VPT;
    const bool act = off0 < Ds;                    // Ds=96: lanes 48..63 idle
    const int off  = act ? off0 : (Ds - VPT);      // clamp: redundant but safe

    const int e0 = rowptr[node], e1 = rowptr[node + 1];
    float acc[VPT];
    #pragma unroll
    for (int i = 0; i < VPT; ++i) acc[i] = 0.0f;

    int e = e0;
    for (; e + 4 <= e1; e += 4) {
        int s0 = csr_src[e + 0];
        int s1 = csr_src[e + 1];
        int s2 = csr_src[e + 2];
        int s3 = csr_src[e + 3];
        T r0 = *(const T*)(feat + (size_t)s0 * Ds + off);
        T r1 = *(const T*)(feat + (size_t)s1 * Ds + off);
        T r2 = *(const T*)(feat + (size_t)s2 * Ds + off);
        T r3 = *(const T*)(feat + (size_t)s3 * Ds + off);
        #pragma unroll
        for (int i = 0; i < VPT; ++i)
            acc[i] += (bf2f(r0[i]) + bf2f(r1[i])) + (bf2f(r2[i]) + bf2f(r3[i]));
    }
    for (; e < e1; ++e) {
        int s = csr_src[e];
        T r = *(const T*)(feat + (size_t)s * Ds + off);
        #pragma unroll
        for (int i = 0; i < VPT; ++i) acc[i] += bf2f(r[i]);
    }

    if (act) {
        T o;
        #pragma unroll
        for (int i = 0; i < VPT; ++i) o[i] = f2bf(acc[i]);
        *(T*)(out + (size_t)node * Ds + off0) = o;
    }
}

// ---------------- bf16 MFMA GEMM, templated N-tile (m97 recipe) -----------------
// out = act( A1@W1t^T + A2@W2t^T + bias ),  A*: bf16 [M][K], W*t: bf16 [Fo][K]
// Tile: 128 rows x (NT*32) cols, BK=32. 256 thr = 4 waves in 2x2;
// each wave: 64 rows x NT*16 cols via 4 x NT MFMA 16x16x32.
// NT=4 -> BN=128 (acc 16 v4f); NT=8 -> BN=256 (acc 32 v4f, 2 waves/SIMD).
template<int NT>
__global__ __launch_bounds__(256, 2)
void mfma_gemm_kernel(const ushort_t* __restrict__ A1,
                      const ushort_t* __restrict__ A2,
                      const ushort_t* __restrict__ W1t,
                      const ushort_t* __restrict__ W2t,
                      const float* __restrict__ bias,
                      void* __restrict__ outp,
                      int M, int K, int Fo, int relu, int out_bf16)
{
    constexpr int BN      = NT * 32;     // tile width
    constexpr int NBT     = NT * 2;      // B n-tiles of 16
    constexpr int BT_PW   = NBT / 4;     // B-tiles staged per wave
    __shared__ ushort_t Al[8 * 512];     // 8 m-tiles x (16 rows x 32 k) lane-order
    __shared__ ushort_t Bl[NBT * 512];
    const int tid = (int)threadIdx.x;
    const int l   = tid & 63;
    const int w   = tid >> 6;
    const int q   = l >> 4;
    const int r15 = l & 15;
    const int bm  = blockIdx.y * 128;
    const int bn  = blockIdx.x * BN;
    const int wm  = w >> 1, wn = w & 1;

    v4f acc[4][NT];
    #pragma unroll
    for (int mt = 0; mt < 4; ++mt)
        #pragma unroll
        for (int nt = 0; nt < NT; ++nt)
            acc[mt][nt] = (v4f){0.0f, 0.0f, 0.0f, 0.0f};

    for (int pass = 0; pass < 2; ++pass) {
        const ushort_t* A  = pass ? A2  : A1;
        const ushort_t* Bt = pass ? W2t : W1t;
        if (A == nullptr) break;
        for (int k0 = 0; k0 < K; k0 += 32) {
            __syncthreads();   // prior frag reads done before LDS overwrite
            #pragma unroll
            for (int ii = 0; ii < 2; ++ii) {
                int it = w * 2 + ii;               // wave-uniform tile id
                int row = bm + it * 16 + r15;
                const ushort_t* ga = A + (size_t)row * K + k0 + q * 8;
                if (row < M) GLOAD_LDS16(ga, Al + it * 512);
            }
            #pragma unroll
            for (int jj = 0; jj < BT_PW; ++jj) {
                int jt = w * BT_PW + jj;
                int col = bn + jt * 16 + r15;      // Fo multiple of BN
                const ushort_t* gb = Bt + (size_t)col * K + k0 + q * 8;
                GLOAD_LDS16(gb, Bl + jt * 512);
            }
            __syncthreads();   // drains vmcnt -> staged data visible
            v8s af[4], bf[NT];
            #pragma unroll
            for (int mt = 0; mt < 4; ++mt)
                af[mt] = *(const v8s*)(Al + (wm * 4 + mt) * 512 + l * 8);
            #pragma unroll
            for (int nt = 0; nt < NT; ++nt)
                bf[nt] = *(const v8s*)(Bl + (wn * NT + nt) * 512 + l * 8);
            #pragma unroll
            for (int mt = 0; mt < 4; ++mt)
                #pragma unroll
                for (int nt = 0; nt < NT; ++nt)
                    acc[mt][nt] = __builtin_amdgcn_mfma_f32_16x16x32_bf16(
                        af[mt], bf[nt], acc[mt][nt], 0, 0, 0);
        }
    }

    // epilogue: C/D map col=lane&15, row=q*4+reg
    #pragma unroll
    for (int nt = 0; nt < NT; ++nt) {
        int col = bn + wn * (NT * 16) + nt * 16 + r15;
        float bb = bias[col];
        #pragma unroll
        for (int mt = 0; mt < 4; ++mt) {
            #pragma unroll
            for (int p = 0; p < 4; ++p) {
                int row = bm + wm * 64 + mt * 16 + q * 4 + p;
                if (row < M) {
                    float v = acc[mt][nt][p] + bb;
                    if (relu) v = fmaxf(v, 0.0f);
                    if (out_bf16) ((ushort_t*)outp)[(size_t)row * Fo + col] = f2bf(v);
                    else          ((float*)outp)[(size_t)row * Fo + col]   = v;
                }
            }
        }
    }
}

// ---------------- LayerNorm(128) + ReLU + x_atom + atomic pool -----------------
__global__ __launch_bounds__(128)
void ln_relu_pool_kernel(const float* __restrict__ z,
                         const float* __restrict__ gamma,
                         const float* __restrict__ beta,
                         const int* __restrict__ batch,
                         float* __restrict__ x_atom,
                         float* __restrict__ pooled)
{
    int row = (int)blockIdx.x;
    int t = (int)threadIdx.x;     // 0..127
    float v = z[(long long)row * 128 + t];

    __shared__ float red[2];
    float s = v;
    #pragma unroll
    for (int o = 32; o >= 1; o >>= 1) s += __shfl_xor(s, o, 64);
    int wave = t >> 6;
    if ((t & 63) == 0) red[wave] = s;
    __syncthreads();
    float mean = (red[0] + red[1]) * (1.0f / 128.0f);

    float d = v - mean;
    float s2 = d * d;
    #pragma unroll
    for (int o = 32; o >= 1; o >>= 1) s2 += __shfl_xor(s2, o, 64);
    __syncthreads();
    if ((t & 63) == 0) red[wave] = s2;
    __syncthreads();
    float var = (red[0] + red[1]) * (1.0f / 128.0f);

    float y = d * rsqrtf(var + 1e-5f) * gamma[t] + beta[t];
    y = fmaxf(y, 0.0f);
    x_atom[(long long)row * 128 + t] = y;
    int b = batch[row];
    if ((unsigned)b < (unsigned)N_GRAPHS)
        atomicAdd(pooled + (long long)b * 128 + t, y);
}

extern "C" void kernel_launch(void* const* d_in, const int* in_sizes, int n_in,
                              void* d_out, int out_size, void* d_ws, size_t ws_size,
                              hipStream_t stream)
{
    const float* x     = (const float*)d_in[0];
    const int*   ei    = (const int*)d_in[1];
    const int*   batch = (const int*)d_in[2];
    const float* W1r   = (const float*)d_in[3];
    const float* b1    = (const float*)d_in[4];
    const float* W1o   = (const float*)d_in[5];
    const float* W2r   = (const float*)d_in[6];
    const float* b2    = (const float*)d_in[7];
    const float* W2o   = (const float*)d_in[8];
    const float* W3r   = (const float*)d_in[9];
    const float* b3    = (const float*)d_in[10];
    const float* W3o   = (const float*)d_in[11];
    const float* Wfc   = (const float*)d_in[12];
    const float* bfc   = (const float*)d_in[13];
    const float* lng   = (const float*)d_in[14];
    const float* lnb   = (const float*)d_in[15];

    const size_t WS_NEED = 204800000;
    if (ws_size < WS_NEED) {
        hipMemsetAsync(d_out, 0, (size_t)out_size * sizeof(float), stream);
        return;
    }

    char* ws = (char*)d_ws;
    // layout (bytes)
    ushort_t* xb   = (ushort_t*)(ws + 0);            // 50000x96 bf16   = 9.6e6
    ushort_t* h1   = (ushort_t*)(ws + 9600000);      // 50000x256 bf16  = 25.6e6
    float*    z    = (float*)   (ws + 0);            // 50000x128 f32 (xb/h1 dead)
    ushort_t* aggr = (ushort_t*)(ws + 35200000);     // up to 50000x512 bf16
    ushort_t* h2   = (ushort_t*)(ws + 86400000);     // 50000x512 bf16
    ushort_t* h3   = (ushort_t*)(ws + 137600000);    // 50000x512 bf16
    int* deg    = (int*)(ws + 188800000);            // 50000
    int* rowptr = (int*)(ws + 189000000);            // 50001
    int* cursor = (int*)(ws + 189200128);            // 50000
    int* csrsrc = (int*)(ws + 189400128);            // 800000
    int* blksum = (int*)(ws + 192600128);            // 64
    ushort_t* wt = (ushort_t*)(ws + 192600512);
    ushort_t* w1r_t = wt;                 // 256x96
    ushort_t* w1o_t = w1r_t + 24576;      // 256x96
    ushort_t* w2r_t = w1o_t + 24576;      // 512x256
    ushort_t* w2o_t = w2r_t + 131072;     // 512x256
    ushort_t* w3r_t = w2o_t + 131072;     // 512x512
    ushort_t* w3o_t = w3r_t + 262144;     // 512x512
    ushort_t* wfc_t = w3o_t + 262144;     // 128x512

    float* x_atom = (float*)d_out;
    float* pooled = x_atom + (size_t)N_NODES * OUT_DIM;

    const int* src = ei;
    const int* dst = ei + N_EDGES;

    // ---- conversions: weights (transpose+pad+bf16), x (pad+bf16) ----
    wt_kernel<<<(256 * K1P + 255) / 256, 256, 0, stream>>>(W1r, w1r_t, IN_DIM, HID, K1P);
    wt_kernel<<<(256 * K1P + 255) / 256, 256, 0, stream>>>(W1o, w1o_t, IN_DIM, HID, K1P);
    wt_kernel<<<(512 * 256 + 255) / 256, 256, 0, stream>>>(W2r, w2r_t, HID, 2 * HID, HID);
    wt_kernel<<<(512 * 256 + 255) / 256, 256, 0, stream>>>(W2o, w2o_t, HID, 2 * HID, HID);
    wt_kernel<<<(512 * 512 + 255) / 256, 256, 0, stream>>>(W3r, w3r_t, 2 * HID, 2 * HID, 2 * HID);
    wt_kernel<<<(512 * 512 + 255) / 256, 256, 0, stream>>>(W3o, w3o_t, 2 * HID, 2 * HID, 2 * HID);
    wt_kernel<<<(128 * 512 + 255) / 256, 256, 0, stream>>>(Wfc, wfc_t, 2 * HID, OUT_DIM, 2 * HID);
    pad_cast_kernel<<<((N_NODES * K1P) + 255) / 256, 256, 0, stream>>>(x, xb, N_NODES, IN_DIM, K1P);

    // ---- CSR build ----
    hipMemsetAsync(deg, 0, N_NODES * sizeof(int), stream);
    hist_kernel<<<(N_EDGES + 255) / 256, 256, 0, stream>>>(dst, deg, N_EDGES);
    {
        int nb = (N_NODES + 1023) / 1024;   // 49
        scan1_kernel<<<nb, 1024, 0, stream>>>(deg, rowptr, blksum, N_NODES);
        scan2_kernel<<<1, 64, 0, stream>>>(blksum, nb);
        scan3_kernel<<<(N_NODES + 1 + 255) / 256, 256, 0, stream>>>(blksum, rowptr, cursor, N_NODES);
    }
    fill_kernel<<<(N_EDGES + 255) / 256, 256, 0, stream>>>(src, dst, cursor, csrsrc, N_EDGES);

    const int GY = (N_NODES + 127) / 128;
    const int AGG_BLKS = (N_NODES + 3) / 4;

    // ---- layer 1: 78(pad96) -> 256 ----
    csr_agg_wave_kernel<2><<<AGG_BLKS, 256, 0, stream>>>(xb, rowptr, csrsrc, aggr, K1P);
    {
        dim3 g(HID / 256, GY);     // 1 x GY : A fetched once
        mfma_gemm_kernel<8><<<g, 256, 0, stream>>>(aggr, xb, w1r_t, w1o_t, b1, h1,
                                                   N_NODES, K1P, HID, 1, 1);
    }
    // ---- layer 2: 256 -> 512 ----
    csr_agg_wave_kernel<4><<<AGG_BLKS, 256, 0, stream>>>(h1, rowptr, csrsrc, aggr, HID);
    {
        dim3 g((2 * HID) / 256, GY);   // 2 col-blocks
        mfma_gemm_kernel<8><<<g, 256, 0, stream>>>(aggr, h1, w2r_t, w2o_t, b2, h2,
                                                   N_NODES, HID, 2 * HID, 1, 1);
    }
    // ---- layer 3: 512 -> 512 ----
    csr_agg_wave_kernel<8><<<AGG_BLKS, 256, 0, stream>>>(h2, rowptr, csrsrc, aggr, 2 * HID);
    {
        dim3 g((2 * HID) / 256, GY);   // 2 col-blocks
        mfma_gemm_kernel<8><<<g, 256, 0, stream>>>(aggr, h2, w3r_t, w3o_t, b3, h3,
                                                   N_NODES, 2 * HID, 2 * HID, 1, 1);
    }
    // ---- fc: 512 -> 128, fp32 out, no relu ----
    {
        dim3 g(OUT_DIM / 128, GY);
        mfma_gemm_kernel<4><<<g, 256, 0, stream>>>(h3, nullptr, wfc_t, nullptr, bfc, z,
                                                   N_NODES, 2 * HID, OUT_DIM, 0, 0);
    }
    // ---- LN + ReLU + pool ----
    hipMemsetAsync(pooled, 0, (size_t)N_GRAPHS * OUT_DIM * sizeof(float), stream);
    ln_relu_pool_kernel<<<N_NODES, 128, 0, stream>>>(z, lng, lnb, batch, x_atom, pooled);
}

// Round 6
// 717.870 us; speedup vs baseline: 7.9061x; 1.0003x over previous
//
#include <hip/hip_runtime.h>

#define N_NODES 50000
#define N_EDGES 800000
#define N_GRAPHS 1024
#define IN_DIM 78
#define K1P 96            // IN_DIM padded to multiple of 32
#define HID 256
#define OUT_DIM 128

typedef unsigned short ushort_t;
typedef __attribute__((ext_vector_type(8))) short v8s;
typedef __attribute__((ext_vector_type(4))) float v4f;
typedef __attribute__((ext_vector_type(4))) unsigned int u4;
typedef __attribute__((ext_vector_type(2))) unsigned short us2;
typedef __attribute__((ext_vector_type(4))) unsigned short us4;
typedef __attribute__((ext_vector_type(8))) unsigned short us8;

__device__ __forceinline__ ushort_t f2bf(float f) {
    unsigned u = __float_as_uint(f);
    unsigned r = (u + 0x7fffu + ((u >> 16) & 1u)) >> 16;   // RNE
    return (ushort_t)r;
}
__device__ __forceinline__ float bf2f(ushort_t h) {
    return __uint_as_float((unsigned)h << 16);
}

// ---------------- weight transpose + pad + bf16 cast: out[n][k] = W[k][n] ------
__global__ __launch_bounds__(256)
void wt_kernel(const float* __restrict__ W, ushort_t* __restrict__ out,
               int K, int N, int Kp)
{
    int i = blockIdx.x * 256 + threadIdx.x;
    if (i >= N * Kp) return;
    int n = i / Kp, k = i - n * Kp;
    float v = (k < K) ? W[(size_t)k * N + n] : 0.0f;
    out[i] = f2bf(v);
}

// ---------------- pad + cast activations: out[r][k<Kin?]=in, else 0 -----------
__global__ __launch_bounds__(256)
void pad_cast_kernel(const float* __restrict__ in, ushort_t* __restrict__ out,
                     int rows, int Kin, int Kout)
{
    int i = blockIdx.x * 256 + threadIdx.x;
    if (i >= rows * Kout) return;
    int r = i / Kout, k = i - r * Kout;
    out[i] = f2bf(k < Kin ? in[(size_t)r * Kin + k] : 0.0f);
}

// ---------------- CSR build ----------------------------------------------------
__global__ __launch_bounds__(256)
void hist_kernel(const int* __restrict__ dstI, int* __restrict__ deg, int nE)
{
    int e = blockIdx.x * 256 + threadIdx.x;
    if (e < nE) {
        int d = dstI[e];
        if ((unsigned)d < (unsigned)N_NODES) atomicAdd(&deg[d], 1);
    }
}

// hierarchical exclusive scan of deg -> rowptr (n+1 entries)
__global__ __launch_bounds__(1024)
void scan1_kernel(const int* __restrict__ deg, int* __restrict__ rowptr,
                  int* __restrict__ blocksum, int n)
{
    __shared__ int s[1024];
    int b = (int)blockIdx.x, t = (int)threadIdx.x;
    int i = b * 1024 + t;
    int v = (i < n) ? deg[i] : 0;
    s[t] = v;
    __syncthreads();
    for (int off = 1; off < 1024; off <<= 1) {
        int a = (t >= off) ? s[t - off] : 0;
        __syncthreads();
        s[t] += a;
        __syncthreads();
    }
    if (i < n) rowptr[i + 1] = s[t];      // block-local inclusive
    if (t == 1023) blocksum[b] = s[1023];
    if (b == 0 && t == 0) rowptr[0] = 0;
}

__global__ __launch_bounds__(64)
void scan2_kernel(int* __restrict__ blocksum, int nb)   // nb <= 64
{
    int t = (int)threadIdx.x;
    int v = (t < nb) ? blocksum[t] : 0;
    #pragma unroll
    for (int off = 1; off < 64; off <<= 1) {
        int a = __shfl_up(v, off, 64);
        if (t >= off) v += a;
    }
    if (t < nb) blocksum[t] = v;
}

__global__ __launch_bounds__(256)
void scan3_kernel(const int* __restrict__ blocksum, int* __restrict__ rowptr,
                  int* __restrict__ cursor, int n)
{
    int j = blockIdx.x * 256 + threadIdx.x;   // 0..n
    if (j > n) return;
    int v;
    if (j == 0) v = 0;
    else {
        int b = (j - 1) >> 10;
        v = rowptr[j] + (b >= 1 ? blocksum[b - 1] : 0);
    }
    rowptr[j] = v;
    if (j < n) cursor[j] = v;
}

__global__ __launch_bounds__(256)
void fill_kernel(const int* __restrict__ srcI, const int* __restrict__ dstI,
                 int* __restrict__ cursor, int* __restrict__ csr_src, int nE)
{
    int e = blockIdx.x * 256 + threadIdx.x;
    if (e < nE) {
        int d = dstI[e];
        int s = srcI[e];
        if ((unsigned)d < (unsigned)N_NODES && (unsigned)s < (unsigned)N_NODES) {
            int pos = atomicAdd(&cursor[d], 1);
            csr_src[pos] = s;
        }
    }
}

// ---------------- CSR aggregation, wave-per-node, vectorized gathers -----------
template<int VPT> struct VecT;
template<> struct VecT<2> { using T = us2; };
template<> struct VecT<4> { using T = us4; };
template<> struct VecT<8> { using T = us8; };

template<int VPT>
__global__ __launch_bounds__(256)
void csr_agg_wave_kernel(const ushort_t* __restrict__ feat,
                         const int* __restrict__ rowptr,
                         const int* __restrict__ csr_src,
                         ushort_t* __restrict__ out, int Ds)
{
    using T = typename VecT<VPT>::T;
    const int wv   = (int)threadIdx.x >> 6;
    const int node = (int)blockIdx.x * 4 + wv;
    if (node >= N_NODES) return;
    const int lane = (int)threadIdx.x & 63;
    const int off0 = lane * VPT;
    const bool act = off0 < Ds;                    // Ds=96: lanes 48..63 idle
    const int off  = act ? off0 : (Ds - VPT);      // clamp: redundant but safe

    const int e0 = rowptr[node], e1 = rowptr[node + 1];
    float acc[VPT];
    #pragma unroll
    for (int i = 0; i < VPT; ++i) acc[i] = 0.0f;

    int e = e0;
    for (; e + 4 <= e1; e += 4) {
        int s0 = csr_src[e + 0];
        int s1 = csr_src[e + 1];
        int s2 = csr_src[e + 2];
        int s3 = csr_src[e + 3];
        T r0 = *(const T*)(feat + (size_t)s0 * Ds + off);
        T r1 = *(const T*)(feat + (size_t)s1 * Ds + off);
        T r2 = *(const T*)(feat + (size_t)s2 * Ds + off);
        T r3 = *(const T*)(feat + (size_t)s3 * Ds + off);
        #pragma unroll
        for (int i = 0; i < VPT; ++i)
            acc[i] += (bf2f(r0[i]) + bf2f(r1[i])) + (bf2f(r2[i]) + bf2f(r3[i]));
    }
    for (; e < e1; ++e) {
        int s = csr_src[e];
        T r = *(const T*)(feat + (size_t)s * Ds + off);
        #pragma unroll
        for (int i = 0; i < VPT; ++i) acc[i] += bf2f(r[i]);
    }

    if (act) {
        T o;
        #pragma unroll
        for (int i = 0; i < VPT; ++i) o[i] = f2bf(acc[i]);
        *(T*)(out + (size_t)node * Ds + off0) = o;
    }
}

// ---------------- bf16 MFMA GEMM, register-pipelined K-loop ---------------------
// out = act( A1@W1t^T + A2@W2t^T + bias ),  A*: bf16 [M][K], W*t: bf16 [Fo][K]
// Tile: 128 rows x (NT*32) cols, BK=32. 256 thr = 4 waves in 2x2;
// each wave: 64 rows x NT*16 cols via 4 x NT MFMA 16x16x32.
// Pipeline: global->VGPR prefetch of step k+1 issued right after the ds_write of
// step k, so L3 latency overlaps the MFMA block (no vmcnt(0)-before-barrier
// drain of global traffic — the m97 plateau).
template<int NT>
__global__ __launch_bounds__(256, 2)
void mfma_gemm_kernel(const ushort_t* __restrict__ A1,
                      const ushort_t* __restrict__ A2,
                      const ushort_t* __restrict__ W1t,
                      const ushort_t* __restrict__ W2t,
                      const float* __restrict__ bias,
                      void* __restrict__ outp,
                      int M, int K, int Fo, int relu, int out_bf16)
{
    constexpr int BN    = NT * 32;     // tile width
    constexpr int NBT   = NT * 2;      // B n-tiles of 16
    constexpr int BT_PW = NBT / 4;     // B-tiles staged per wave
    __shared__ __align__(16) ushort_t Al[8 * 512];   // 8 m-tiles, lane-ordered
    __shared__ __align__(16) ushort_t Bl[NBT * 512];
    const int tid = (int)threadIdx.x;
    const int l   = tid & 63;
    const int w   = tid >> 6;
    const int q   = l >> 4;
    const int r15 = l & 15;
    const int bm  = blockIdx.y * 128;
    const int bn  = blockIdx.x * BN;
    const int wm  = w >> 1, wn = w & 1;

    const int s1 = K >> 5;                       // steps per pass
    const int nsteps = A2 ? (2 * s1) : s1;

    v4f acc[4][NT];
    #pragma unroll
    for (int mt = 0; mt < 4; ++mt)
        #pragma unroll
        for (int nt = 0; nt < NT; ++nt)
            acc[mt][nt] = (v4f){0.0f, 0.0f, 0.0f, 0.0f};

    u4 ra[2], rb[BT_PW];
    auto load_step = [&](int step) {
        const ushort_t* A  = (step >= s1) ? A2  : A1;
        const ushort_t* Bt = (step >= s1) ? W2t : W1t;
        const int k0 = ((step >= s1) ? (step - s1) : step) << 5;
        #pragma unroll
        for (int ii = 0; ii < 2; ++ii) {
            int it  = w * 2 + ii;
            int row = bm + it * 16 + r15;
            if (row < M) ra[ii] = *(const u4*)(A + (size_t)row * K + k0 + q * 8);
            else         ra[ii] = (u4){0u, 0u, 0u, 0u};
        }
        #pragma unroll
        for (int jj = 0; jj < BT_PW; ++jj) {
            int jt  = w * BT_PW + jj;
            int col = bn + jt * 16 + r15;          // Fo multiple of BN
            rb[jj] = *(const u4*)(Bt + (size_t)col * K + k0 + q * 8);
        }
    };

    load_step(0);
    for (int step = 0; step < nsteps; ++step) {
        __syncthreads();   // prior frag reads done before LDS overwrite
        #pragma unroll
        for (int ii = 0; ii < 2; ++ii)
            *(u4*)(Al + (size_t)(w * 2 + ii) * 512 + l * 8) = ra[ii];
        #pragma unroll
        for (int jj = 0; jj < BT_PW; ++jj)
            *(u4*)(Bl + (size_t)(w * BT_PW + jj) * 512 + l * 8) = rb[jj];
        if (step + 1 < nsteps) load_step(step + 1);   // in flight across MFMAs
        __syncthreads();   // LDS writes visible
        v8s af[4], bf[NT];
        #pragma unroll
        for (int mt = 0; mt < 4; ++mt)
            af[mt] = *(const v8s*)(Al + (size_t)(wm * 4 + mt) * 512 + l * 8);
        #pragma unroll
        for (int nt = 0; nt < NT; ++nt)
            bf[nt] = *(const v8s*)(Bl + (size_t)(wn * NT + nt) * 512 + l * 8);
        #pragma unroll
        for (int mt = 0; mt < 4; ++mt)
            #pragma unroll
            for (int nt = 0; nt < NT; ++nt)
                acc[mt][nt] = __builtin_amdgcn_mfma_f32_16x16x32_bf16(
                    af[mt], bf[nt], acc[mt][nt], 0, 0, 0);
    }

    // epilogue: C/D map col=lane&15, row=q*4+reg
    #pragma unroll
    for (int nt = 0; nt < NT; ++nt) {
        int col = bn + wn * (NT * 16) + nt * 16 + r15;
        float bb = bias[col];
        #pragma unroll
        for (int mt = 0; mt < 4; ++mt) {
            #pragma unroll
            for (int p = 0; p < 4; ++p) {
                int row = bm + wm * 64 + mt * 16 + q * 4 + p;
                if (row < M) {
                    float v = acc[mt][nt][p] + bb;
                    if (relu) v = fmaxf(v, 0.0f);
                    if (out_bf16) ((ushort_t*)outp)[(size_t)row * Fo + col] = f2bf(v);
                    else          ((float*)outp)[(size_t)row * Fo + col]   = v;
                }
            }
        }
    }
}

// ---------------- LayerNorm(128) + ReLU + x_atom + atomic pool -----------------
__global__ __launch_bounds__(128)
void ln_relu_pool_kernel(const float* __restrict__ z,
                         const float* __restrict__ gamma,
                         const float* __restrict__ beta,
                         const int* __restrict__ batch,
                         float* __restrict__ x_atom,
                         float* __restrict__ pooled)
{
    int row = (int)blockIdx.x;
    int t = (int)threadIdx.x;     // 0..127
    float v = z[(long long)row * 128 + t];

    __shared__ float red[2];
    float s = v;
    #pragma unroll
    for (int o = 32; o >= 1; o >>= 1) s += __shfl_xor(s, o, 64);
    int wave = t >> 6;
    if ((t & 63) == 0) red[wave] = s;
    __syncthreads();
    float mean = (red[0] + red[1]) * (1.0f / 128.0f);

    float d = v - mean;
    float s2 = d * d;
    #pragma unroll
    for (int o = 32; o >= 1; o >>= 1) s2 += __shfl_xor(s2, o, 64);
    __syncthreads();
    if ((t & 63) == 0) red[wave] = s2;
    __syncthreads();
    float var = (red[0] + red[1]) * (1.0f / 128.0f);

    float y = d * rsqrtf(var + 1e-5f) * gamma[t] + beta[t];
    y = fmaxf(y, 0.0f);
    x_atom[(long long)row * 128 + t] = y;
    int b = batch[row];
    if ((unsigned)b < (unsigned)N_GRAPHS)
        atomicAdd(pooled + (long long)b * 128 + t, y);
}

extern "C" void kernel_launch(void* const* d_in, const int* in_sizes, int n_in,
                              void* d_out, int out_size, void* d_ws, size_t ws_size,
                              hipStream_t stream)
{
    const float* x     = (const float*)d_in[0];
    const int*   ei    = (const int*)d_in[1];
    const int*   batch = (const int*)d_in[2];
    const float* W1r   = (const float*)d_in[3];
    const float* b1    = (const float*)d_in[4];
    const float* W1o   = (const float*)d_in[5];
    const float* W2r   = (const float*)d_in[6];
    const float* b2    = (const float*)d_in[7];
    const float* W2o   = (const float*)d_in[8];
    const float* W3r   = (const float*)d_in[9];
    const float* b3    = (const float*)d_in[10];
    const float* W3o   = (const float*)d_in[11];
    const float* Wfc   = (const float*)d_in[12];
    const float* bfc   = (const float*)d_in[13];
    const float* lng   = (const float*)d_in[14];
    const float* lnb   = (const float*)d_in[15];

    const size_t WS_NEED = 204800000;
    if (ws_size < WS_NEED) {
        hipMemsetAsync(d_out, 0, (size_t)out_size * sizeof(float), stream);
        return;
    }

    char* ws = (char*)d_ws;
    // layout (bytes)
    ushort_t* xb   = (ushort_t*)(ws + 0);            // 50000x96 bf16   = 9.6e6
    ushort_t* h1   = (ushort_t*)(ws + 9600000);      // 50000x256 bf16  = 25.6e6
    float*    z    = (float*)   (ws + 0);            // 50000x128 f32 (xb/h1 dead)
    ushort_t* aggr = (ushort_t*)(ws + 35200000);     // up to 50000x512 bf16
    ushort_t* h2   = (ushort_t*)(ws + 86400000);     // 50000x512 bf16
    ushort_t* h3   = (ushort_t*)(ws + 137600000);    // 50000x512 bf16
    int* deg    = (int*)(ws + 188800000);            // 50000
    int* rowptr = (int*)(ws + 189000000);            // 50001
    int* cursor = (int*)(ws + 189200128);            // 50000
    int* csrsrc = (int*)(ws + 189400128);            // 800000
    int* blksum = (int*)(ws + 192600128);            // 64
    ushort_t* wt = (ushort_t*)(ws + 192600512);
    ushort_t* w1r_t = wt;                 // 256x96
    ushort_t* w1o_t = w1r_t + 24576;      // 256x96
    ushort_t* w2r_t = w1o_t + 24576;      // 512x256
    ushort_t* w2o_t = w2r_t + 131072;     // 512x256
    ushort_t* w3r_t = w2o_t + 131072;     // 512x512
    ushort_t* w3o_t = w3r_t + 262144;     // 512x512
    ushort_t* wfc_t = w3o_t + 262144;     // 128x512

    float* x_atom = (float*)d_out;
    float* pooled = x_atom + (size_t)N_NODES * OUT_DIM;

    const int* src = ei;
    const int* dst = ei + N_EDGES;

    // ---- conversions: weights (transpose+pad+bf16), x (pad+bf16) ----
    wt_kernel<<<(256 * K1P + 255) / 256, 256, 0, stream>>>(W1r, w1r_t, IN_DIM, HID, K1P);
    wt_kernel<<<(256 * K1P + 255) / 256, 256, 0, stream>>>(W1o, w1o_t, IN_DIM, HID, K1P);
    wt_kernel<<<(512 * 256 + 255) / 256, 256, 0, stream>>>(W2r, w2r_t, HID, 2 * HID, HID);
    wt_kernel<<<(512 * 256 + 255) / 256, 256, 0, stream>>>(W2o, w2o_t, HID, 2 * HID, HID);
    wt_kernel<<<(512 * 512 + 255) / 256, 256, 0, stream>>>(W3r, w3r_t, 2 * HID, 2 * HID, 2 * HID);
    wt_kernel<<<(512 * 512 + 255) / 256, 256, 0, stream>>>(W3o, w3o_t, 2 * HID, 2 * HID, 2 * HID);
    wt_kernel<<<(128 * 512 + 255) / 256, 256, 0, stream>>>(Wfc, wfc_t, 2 * HID, OUT_DIM, 2 * HID);
    pad_cast_kernel<<<((N_NODES * K1P) + 255) / 256, 256, 0, stream>>>(x, xb, N_NODES, IN_DIM, K1P);

    // ---- CSR build ----
    hipMemsetAsync(deg, 0, N_NODES * sizeof(int), stream);
    hist_kernel<<<(N_EDGES + 255) / 256, 256, 0, stream>>>(dst, deg, N_EDGES);
    {
        int nb = (N_NODES + 1023) / 1024;   // 49
        scan1_kernel<<<nb, 1024, 0, stream>>>(deg, rowptr, blksum, N_NODES);
        scan2_kernel<<<1, 64, 0, stream>>>(blksum, nb);
        scan3_kernel<<<(N_NODES + 1 + 255) / 256, 256, 0, stream>>>(blksum, rowptr, cursor, N_NODES);
    }
    fill_kernel<<<(N_EDGES + 255) / 256, 256, 0, stream>>>(src, dst, cursor, csrsrc, N_EDGES);

    const int GY = (N_NODES + 127) / 128;
    const int AGG_BLKS = (N_NODES + 3) / 4;

    // ---- layer 1: 78(pad96) -> 256 ----
    csr_agg_wave_kernel<2><<<AGG_BLKS, 256, 0, stream>>>(xb, rowptr, csrsrc, aggr, K1P);
    {
        dim3 g(HID / 256, GY);     // 1 x GY : A fetched once
        mfma_gemm_kernel<8><<<g, 256, 0, stream>>>(aggr, xb, w1r_t, w1o_t, b1, h1,
                                                   N_NODES, K1P, HID, 1, 1);
    }
    // ---- layer 2: 256 -> 512 ----
    csr_agg_wave_kernel<4><<<AGG_BLKS, 256, 0, stream>>>(h1, rowptr, csrsrc, aggr, HID);
    {
        dim3 g((2 * HID) / 256, GY);   // 2 col-blocks
        mfma_gemm_kernel<8><<<g, 256, 0, stream>>>(aggr, h1, w2r_t, w2o_t, b2, h2,
                                                   N_NODES, HID, 2 * HID, 1, 1);
    }
    // ---- layer 3: 512 -> 512 ----
    csr_agg_wave_kernel<8><<<AGG_BLKS, 256, 0, stream>>>(h2, rowptr, csrsrc, aggr, 2 * HID);
    {
        dim3 g((2 * HID) / 256, GY);   // 2 col-blocks
        mfma_gemm_kernel<8><<<g, 256, 0, stream>>>(aggr, h2, w3r_t, w3o_t, b3, h3,
                                                   N_NODES, 2 * HID, 2 * HID, 1, 1);
    }
    // ---- fc: 512 -> 128, fp32 out, no relu ----
    {
        dim3 g(OUT_DIM / 128, GY);
        mfma_gemm_kernel<4><<<g, 256, 0, stream>>>(h3, nullptr, wfc_t, nullptr, bfc, z,
                                                   N_NODES, 2 * HID, OUT_DIM, 0, 0);
    }
    // ---- LN + ReLU + pool ----
    hipMemsetAsync(pooled, 0, (size_t)N_GRAPHS * OUT_DIM * sizeof(float), stream);
    ln_relu_pool_kernel<<<N_NODES, 128, 0, stream>>>(z, lng, lnb, batch, x_atom, pooled);
}